// Round 11
// baseline (837.746 us; speedup 1.0000x reference)
//
#include <hip/hip_runtime.h>

// Conv2d 3x3 SAME, stride 1: x (16,64,256,256) f32, w (128,64,3,3), bias (128) -> out (16,128,256,256)
//
// V12: fused implicit-GEMM on mfma_f32_32x32x16_f16 (2x FLOP per LDS byte vs 16x16x32).
//  - Fused staging (V11): conv reads x f32 directly, cvt->f16, ds_write swizzled tiles.
//  - 256 blocks (4 strips x 4 bands x 16 n) x 512 thr; 8 waves = 4 cout-groups(32) x 2 px-halves(32).
//  - A (weights) register-persistent: 32 couts x 64ci x 9 taps / 64 lanes = 144 VGPR.
//    Staging loads issued MID-epilogue (acc half-dead) to keep peak VGPR < 256 (V6 remat trap).
//  - LDS ring: 10 slots x 66 cols x 136 B (pad 128->136: col stride no longer ≡ 0 mod 32 banks
//    -> 32-lane-wide b128 reads ~2-way = free). 16B-unit XOR ((s^(c&7))<<4) on both sides.
//  - Inner loop: 72 ds_read_b128 + 144 MFMA per lane per iter (was 144 + 288@16x16).
//  - Swapped operands mfma(x_frag, w_frag, acc): D col=lane&31=cout, row=4*(l>>5)+8q+r = px
//    (m74/m101-verified 32x32 layout) -> acc = 16x float4 of 4 consecutive px.
//  - Epilogue: esc transpose (stride 33 floats, conflict-checked) -> NT dwordx4, 8 lanes/line
//    = full 128B lines. Raw s_barrier + lgkmcnt(0) only; NT stores never drained.

typedef _Float16 half8_t __attribute__((ext_vector_type(8)));
typedef float floatx4 __attribute__((ext_vector_type(4)));
typedef float floatx16 __attribute__((ext_vector_type(16)));

#define HH 256
#define WW 256
#define CIN 64
#define COUT 128
#define NB 16

#define ROWB  8976               // 66 cols * 136 B
#define NSLOT 10

// ---------- pass 1a: weights OIHW f32 -> w_t[9][8][128][8] f16 ----------
__global__ void Conv2d_wprep_kernel(const float* __restrict__ w, _Float16* __restrict__ w_t) {
    int idx = blockIdx.x * 256 + threadIdx.x;
    if (idx >= 9 * 8 * 128 * 8) return;
    const int j = idx & 7, cout = (idx >> 3) & 127, s = (idx >> 10) & 7, t = idx >> 13;
    w_t[idx] = (_Float16)w[(cout * 64 + s * 8 + j) * 9 + t];
}

// ---------- fused conv ----------
__global__ __launch_bounds__(512, 2) void Conv2dManual_77695958385099_kernel(
    const float* __restrict__ x, const _Float16* __restrict__ w_t,
    const float* __restrict__ bias, float* __restrict__ out) {
    __shared__ __align__(16) unsigned char xs[NSLOT * ROWB];   // 89760 B
    __shared__ __align__(16) float esc[8][1056];               // 33792 B
    const int tid = threadIdx.x;
    const int l = tid & 63, wv = tid >> 6;
    const int wc = wv >> 1;                     // cout-group: couts wc*32..+31
    const int wp = wv & 1;                      // px-half: cols wp*32..+31
    const int l31 = l & 31, hi = l >> 5;
    const int ow0 = blockIdx.x * 64;
    const int band = blockIdx.y;
    const int n = blockIdx.z;
    const int P0 = band * 64;

    // staging roles: 4 row-groups of 128 threads (V11-verbatim)
    const int rw = tid >> 7;
    const int t7 = tid & 127;
    const int su = t7 & 7;                      // ci-granule (8 ci)
    const int cb = t7 >> 3;                     // col block (4 cols)
    const bool isEdge = (t7 >= 120);
    const int eu = t7 - 120;

    // ---- persistent weights: A[tap][ks], 36 x half8 = 144 VGPR; lane l31 -> cout ----
    const char* wl = (const char*)w_t + (wc * 32 + l31) * 16;
    half8_t A[9][4];
#pragma unroll
    for (int tp = 0; tp < 9; ++tp)
#pragma unroll
        for (int ks = 0; ks < 4; ++ks)
            A[tp][ks] = *(const half8_t*)(wl + (tp * 8 + ks * 2 + hi) * 2048);

    const float bv = bias[wc * 32 + l31];

    // ---- per-lane x-read byte offsets: RF[kx][ks] ----
    int RF[3][4];
#pragma unroll
    for (int kx = 0; kx < 3; ++kx) {
        const int c = wp * 32 + kx + l31;
#pragma unroll
        for (int ks = 0; ks < 4; ++ks)
            RF[kx][ks] = c * 136 + (((ks * 2 + hi) ^ (c & 7)) << 4);
    }

    // ---- staging helpers (both-sides swizzle; reg zero-fill = border) ----
    auto stage_load = [&](int pr, float4 (&ld)[8], float (&e0)[8], float (&e1)[8]) {
        const int gr = pr - 1;
        const bool vrow = ((unsigned)gr < 256u);
        if (vrow) {
            const float4* xr = (const float4*)x +
                               (((size_t)(n * 64 + su * 8)) << 14) +
                               (size_t)gr * 64 + (ow0 >> 2) + cb;
#pragma unroll
            for (int j = 0; j < 8; ++j) ld[j] = xr[(size_t)j << 14];
        } else {
#pragma unroll
            for (int j = 0; j < 8; ++j) ld[j] = (float4){0.f, 0.f, 0.f, 0.f};
        }
        if (isEdge) {
            const float* xe = x + (((size_t)(n * 64 + eu * 8)) << 16) + (size_t)gr * 256;
#pragma unroll
            for (int j = 0; j < 8; ++j) {
                e0[j] = (vrow && ow0 > 0)        ? xe[((size_t)j << 16) + ow0 - 1]  : 0.f;
                e1[j] = (vrow && ow0 + 64 < 256) ? xe[((size_t)j << 16) + ow0 + 64] : 0.f;
            }
        }
    };
    auto stage_write = [&](int pr, const float4 (&ld)[8], const float (&e0)[8],
                           const float (&e1)[8]) {
        const unsigned sb = (unsigned)(pr % NSLOT) * ROWB;
#pragma unroll
        for (int k = 0; k < 4; ++k) {
            const int c = 1 + cb * 4 + k;
            half8_t hv;
#pragma unroll
            for (int j = 0; j < 8; ++j) hv[j] = (_Float16)((const float*)&ld[j])[k];
            *(half8_t*)(xs + sb + c * 136 + ((su ^ (c & 7)) << 4)) = hv;
        }
        if (isEdge) {
            half8_t h0, h1;
#pragma unroll
            for (int j = 0; j < 8; ++j) {
                h0[j] = (_Float16)e0[j];
                h1[j] = (_Float16)e1[j];
            }
            *(half8_t*)(xs + sb + (eu << 4)) = h0;                          // c = 0
            *(half8_t*)(xs + sb + 65 * 136 + ((eu ^ 1) << 4)) = h1;         // c = 65
        }
    };

    // ---- prologue: stage padded rows P0..P0+5 ----
    {
        float4 ld[8]; float e0[8], e1[8];
        stage_load(P0 + rw, ld, e0, e1);
        stage_write(P0 + rw, ld, e0, e1);
        if (rw < 2) {
            stage_load(P0 + 4 + rw, ld, e0, e1);
            stage_write(P0 + 4 + rw, ld, e0, e1);
        }
    }
    asm volatile("s_waitcnt lgkmcnt(0)" ::: "memory");
    __builtin_amdgcn_s_barrier();
    __builtin_amdgcn_sched_barrier(0);

    int s0 = P0 % NSLOT;
#pragma unroll 1
    for (int it = 0; it < 16; ++it) {
        int roff[6];
#pragma unroll
        for (int tt = 0; tt < 6; ++tt) {
            int st = s0 + tt;
            if (st >= NSLOT) st -= NSLOT;
            roff[tt] = st * ROWB;
        }

        floatx16 acc[4];
#pragma unroll
        for (int rr = 0; rr < 4; ++rr)
#pragma unroll
            for (int i = 0; i < 16; ++i) acc[rr][i] = bv;

#pragma unroll
        for (int ks = 0; ks < 4; ++ks)
#pragma unroll
            for (int kx = 0; kx < 3; ++kx) {
                half8_t bt[6];
#pragma unroll
                for (int tt = 0; tt < 6; ++tt)
                    bt[tt] = *(const half8_t*)(xs + RF[kx][ks] + roff[tt]);
#pragma unroll
                for (int ky = 0; ky < 3; ++ky) {
                    const half8_t af = A[ky * 3 + kx][ks];
#pragma unroll
                    for (int rr = 0; rr < 4; ++rr)
                        acc[rr] = __builtin_amdgcn_mfma_f32_32x32x16_f16(
                            bt[rr + ky], af, acc[rr], 0, 0, 0);   // D: row=px, col=cout
                }
            }

        // ---- epilogue (rr 0..1) ----
        float* scr = &esc[wv][0];
        const int orow0 = P0 + it * 4;
        float* obase = out + ((size_t)(n * 128 + wc * 32)) * 65536 +
                       (size_t)orow0 * 256 + ow0 + wp * 32;
#pragma unroll
        for (int rr = 0; rr < 2; ++rr) {
#pragma unroll
            for (int q = 0; q < 4; ++q) {
                floatx4 v = {acc[rr][q * 4], acc[rr][q * 4 + 1],
                             acc[rr][q * 4 + 2], acc[rr][q * 4 + 3]};
                *(floatx4*)(scr + l31 * 33 + hi * 4 + q * 8) = v;
            }
#pragma unroll
            for (int p = 0; p < 4; ++p) {
                const int co = p * 8 + (l >> 3);
                const floatx4 vv = *(const floatx4*)(scr + co * 33 + (l & 7) * 4);
                __builtin_nontemporal_store(
                    vv, (floatx4*)(obase + (size_t)co * 65536 + rr * 256 + (l & 7) * 4));
            }
        }

        // ---- MID: issue next-tile f32 loads (acc half-dead -> VGPR fits) ----
        float4 ld[8]; float e0[8], e1[8];
        const int prn = P0 + it * 4 + 6 + rw;
        if (it < 15) stage_load(prn, ld, e0, e1);

        // ---- epilogue (rr 2..3) overlaps load latency ----
#pragma unroll
        for (int rr = 2; rr < 4; ++rr) {
#pragma unroll
            for (int q = 0; q < 4; ++q) {
                floatx4 v = {acc[rr][q * 4], acc[rr][q * 4 + 1],
                             acc[rr][q * 4 + 2], acc[rr][q * 4 + 3]};
                *(floatx4*)(scr + l31 * 33 + hi * 4 + q * 8) = v;
            }
#pragma unroll
            for (int p = 0; p < 4; ++p) {
                const int co = p * 8 + (l >> 3);
                const floatx4 vv = *(const floatx4*)(scr + co * 33 + (l & 7) * 4);
                __builtin_nontemporal_store(
                    vv, (floatx4*)(obase + (size_t)co * 65536 + rr * 256 + (l & 7) * 4));
            }
        }

        // ---- LATE: cvt + ds_write next tile; barrier publishes ----
        if (it < 15) {
            stage_write(prn, ld, e0, e1);     // compiler waits loads, not NT stores
            asm volatile("s_waitcnt lgkmcnt(0)" ::: "memory");
            __builtin_amdgcn_s_barrier();
            __builtin_amdgcn_sched_barrier(0);
        }
        s0 += 4;
        if (s0 >= NSLOT) s0 -= NSLOT;
    }
}

// ---------- fallback (proven V2 fp32) if workspace too small ----------
__global__ __launch_bounds__(256) void Conv2d_fallback_kernel(
    const float* __restrict__ x, const float* __restrict__ w,
    const float* __restrict__ bias, float* __restrict__ out) {
    const int tx = threadIdx.x & 15, ty = threadIdx.x >> 4;
    const int ow0 = blockIdx.x * 64 + tx * 4;
    const int oh = blockIdx.y * 16 + ty;
    const int gg = blockIdx.z & 7, n = blockIdx.z >> 3;
    const int co = gg * 16;
    float acc[16][4];
#pragma unroll
    for (int c = 0; c < 16; ++c) {
        const float b = bias[co + c];
#pragma unroll
        for (int p = 0; p < 4; ++p) acc[c][p] = b;
    }
    const float* xn = x + (size_t)n * CIN * HH * WW;
    const float* wb = w + (size_t)co * CIN * 9;
    for (int ci = 0; ci < CIN; ++ci) {
        const float* xc = xn + (size_t)ci * HH * WW;
        float in[3][6];
#pragma unroll
        for (int ky = 0; ky < 3; ++ky) {
            const int iy = oh + ky - 1;
            if ((unsigned)iy < (unsigned)HH) {
                const float* row = xc + iy * WW;
                const float4 v = *(const float4*)(row + ow0);
                in[ky][1] = v.x; in[ky][2] = v.y; in[ky][3] = v.z; in[ky][4] = v.w;
                in[ky][0] = (ow0 > 0) ? row[ow0 - 1] : 0.0f;
                in[ky][5] = (ow0 < WW - 4) ? row[ow0 + 4] : 0.0f;
            } else {
#pragma unroll
                for (int j = 0; j < 6; ++j) in[ky][j] = 0.0f;
            }
        }
        const float* wc2 = wb + ci * 9;
#pragma unroll
        for (int c = 0; c < 16; ++c) {
            const float* wcc = wc2 + (size_t)c * CIN * 9;
#pragma unroll
            for (int ky = 0; ky < 3; ++ky)
#pragma unroll
                for (int kx = 0; kx < 3; ++kx) {
                    const float wv2 = wcc[ky * 3 + kx];
#pragma unroll
                    for (int p = 0; p < 4; ++p) acc[c][p] += in[ky][kx + p] * wv2;
                }
        }
    }
    const size_t hw = (size_t)HH * WW;
    float* ob = out + ((size_t)n * COUT + co) * hw + (size_t)oh * WW + ow0;
#pragma unroll
    for (int c = 0; c < 16; ++c) {
        float4 v;
        v.x = acc[c][0]; v.y = acc[c][1]; v.z = acc[c][2]; v.w = acc[c][3];
        *(float4*)(ob + (size_t)c * hw) = v;
    }
}

extern "C" void kernel_launch(void* const* d_in, const int* in_sizes, int n_in,
                              void* d_out, int out_size, void* d_ws, size_t ws_size,
                              hipStream_t stream) {
    const float* x = (const float*)d_in[0];
    const float* w = (const float*)d_in[1];
    const float* b = (const float*)d_in[2];
    float* out = (float*)d_out;

    const size_t wt_bytes = (size_t)9 * 8 * 128 * 8 * 2;      // 144 KiB

    if (ws_size >= wt_bytes) {
        _Float16* w_t = (_Float16*)d_ws;
        Conv2d_wprep_kernel<<<dim3(288), 256, 0, stream>>>(w, w_t);
        Conv2dManual_77695958385099_kernel<<<dim3(4, 4, 16), 512, 0, stream>>>(
            x, w_t, b, out);
    } else {
        dim3 grid(WW / 64, HH / 16, NB * (COUT / 16));
        Conv2d_fallback_kernel<<<grid, 256, 0, stream>>>(x, w, b, out);
    }
}

// Round 12
// 773.003 us; speedup vs baseline: 1.0838x; 1.0838x over previous
//
#include <hip/hip_runtime.h>

// Conv2d 3x3 SAME, stride 1: x (16,64,256,256) f32, w (128,64,3,3), bias (128) -> out (16,128,256,256)
//
// V13 = V11 (best, 750us) + occupancy pin + software-pipelined inner loop.
//  - V12 evidence: VGPR_Count=128 with 144 VGPR of declared weights => compiler remats
//    weight loads to hit a 4-waves/EU register tier (per-SIMD VGPR pool = 512; >128 regs
//    caps at 2 waves/SIMD anyway). FIX: amdgpu_waves_per_eu(2,2) pins the tier so
//    A[2][9] (72 VGPR) is truly register-resident.
//  - Inner loop: 24 batches (kx,h,cgf); bt double-buffer (btA/btB, static names) issues
//    batch t+1's 6 ds_reads before batch t's 12 MFMAs -> ds latency hidden, counted lgkmcnt.
//  - Edge halo staged LATE inline (8 lanes: load+cvt+ds_write) -> -16 VGPR held across MFMA.
//  - Everything else V11-verbatim: fused f32->f16 staging (both-sides swizzle), 10-slot ring,
//    swapped mfma(bt,af,acc) D row=pixel, esc b128 transpose -> NT full-line stores,
//    raw s_barrier + lgkmcnt(0) only (NT stores never drained).

typedef _Float16 half8_t __attribute__((ext_vector_type(8)));
typedef float floatx4 __attribute__((ext_vector_type(4)));

#define HH 256
#define WW 256
#define CIN 64
#define COUT 128
#define NB 16

#define ROW_LDS 8448              // bytes per LDS tile row (66 cols * 128 B)
#define NSLOT   10

// ---------- pass 1a: weights OIHW f32 -> w_t[9][8][128][8] f16 ----------
__global__ void Conv2d_wprep_kernel(const float* __restrict__ w, _Float16* __restrict__ w_t) {
    int idx = blockIdx.x * 256 + threadIdx.x;
    if (idx >= 9 * 8 * 128 * 8) return;
    const int j = idx & 7, cout = (idx >> 3) & 127, s = (idx >> 10) & 7, t = idx >> 13;
    w_t[idx] = (_Float16)w[(cout * 64 + s * 8 + j) * 9 + t];
}

// ---------- fused conv ----------
__global__ __launch_bounds__(512)
__attribute__((amdgpu_waves_per_eu(2, 2)))
void Conv2dManual_77695958385099_kernel(
    const float* __restrict__ x, const _Float16* __restrict__ w_t,
    const float* __restrict__ bias, float* __restrict__ out) {
    __shared__ __align__(16) unsigned char xs[NSLOT * ROW_LDS];  // 84480 B
    __shared__ __align__(16) float esc[8][1088];                 // 34816 B
    const int tid = threadIdx.x;
    const int l = tid & 63, wvid = tid >> 6;    // wave -> couts wvid*16..+15
    const int g = l >> 4, ln = l & 15;
    const int ow0 = blockIdx.x * 64;
    const int band = blockIdx.y;                // output rows band*64..+63
    const int n = blockIdx.z;
    const int P0 = band * 64;

    // staging roles: 4 row-groups of 128 threads
    const int rw = tid >> 7;
    const int t7 = tid & 127;
    const int su = t7 & 7;                      // ci-unit (8 ci)
    const int cb = t7 >> 3;                     // col block 0..15 (4 cols each)
    const bool isEdge = (t7 >= 120);            // 8 lanes/row-group: halo cols
    const int eu = t7 - 120;

    // ---- persistent weights: A[h][tap], 18 x half8 = 72 VGPR (occupancy-pinned) ----
    const char* wl = (const char*)w_t + g * 2048 + (wvid * 16 + ln) * 16;
    half8_t A[2][9];
#pragma unroll
    for (int h = 0; h < 2; ++h)
#pragma unroll
        for (int tp = 0; tp < 9; ++tp)
            A[h][tp] = *(const half8_t*)(wl + h * 8192 + tp * 16384);

    const float bv = bias[wvid * 16 + ln];

    // ---- per-lane LDS byte offsets: F[cgf][kx][h] (verified formula) ----
    int F[4][3][2];
#pragma unroll
    for (int cgf = 0; cgf < 4; ++cgf)
#pragma unroll
        for (int kx = 0; kx < 3; ++kx)
#pragma unroll
            for (int h = 0; h < 2; ++h) {
                const int c = cgf * 16 + kx + ln;
                F[cgf][kx][h] = c * 128 + (((4 * h + g) ^ (c & 7)) << 4);
            }

    // ---- staging: main loads early (held in regs); edge handled late inline ----
    auto stage_load = [&](int pr, float4 (&ld)[8]) {
        const int gr = pr - 1;
        if ((unsigned)gr < 256u) {
            const float4* xr = (const float4*)x +
                               (((size_t)(n * 64 + su * 8)) << 14) +
                               (size_t)gr * 64 + (ow0 >> 2) + cb;
#pragma unroll
            for (int j = 0; j < 8; ++j) ld[j] = xr[(size_t)j << 14];
        } else {
#pragma unroll
            for (int j = 0; j < 8; ++j) ld[j] = (float4){0.f, 0.f, 0.f, 0.f};
        }
    };
    auto stage_write = [&](int pr, const float4 (&ld)[8]) {
        const unsigned sb = (unsigned)(pr % NSLOT) * ROW_LDS;
#pragma unroll
        for (int k = 0; k < 4; ++k) {
            const int c = 1 + cb * 4 + k;
            half8_t hv;
#pragma unroll
            for (int j = 0; j < 8; ++j) hv[j] = (_Float16)((const float*)&ld[j])[k];
            *(half8_t*)(xs + sb + c * 128 + ((su ^ (c & 7)) << 4)) = hv;
        }
        if (isEdge) {   // late inline: load halo cols, cvt, write (8 lanes only)
            const int gr = pr - 1;
            const bool vrow = ((unsigned)gr < 256u);
            const float* xe = x + (((size_t)(n * 64 + eu * 8)) << 16) + (size_t)gr * 256;
            half8_t h0, h1;
#pragma unroll
            for (int j = 0; j < 8; ++j) {
                h0[j] = (_Float16)((vrow && ow0 > 0)        ? xe[((size_t)j << 16) + ow0 - 1]  : 0.f);
                h1[j] = (_Float16)((vrow && ow0 + 64 < 256) ? xe[((size_t)j << 16) + ow0 + 64] : 0.f);
            }
            *(half8_t*)(xs + sb + (eu << 4)) = h0;                      // c = 0
            *(half8_t*)(xs + sb + 65 * 128 + ((eu ^ 1) << 4)) = h1;     // c = 65
        }
    };

    // ---- prologue: stage padded rows P0..P0+5 ----
    {
        float4 ld[8];
        stage_load(P0 + rw, ld);
        stage_write(P0 + rw, ld);
        if (rw < 2) {
            stage_load(P0 + 4 + rw, ld);
            stage_write(P0 + 4 + rw, ld);
        }
    }
    asm volatile("s_waitcnt lgkmcnt(0)" ::: "memory");
    __builtin_amdgcn_s_barrier();
    __builtin_amdgcn_sched_barrier(0);

// batch b (0..23): kx = b>>3, h = (b>>2)&1, cgf = b&3  (cgf fastest -> adjacent
// batches hit different acc regs = independent chains)
#define LOADB(DST, B)                                                           \
    {                                                                           \
        const unsigned char* bp_ = xs + F[(B) & 3][(B) >> 3][((B) >> 2) & 1];   \
        _Pragma("unroll")                                                       \
        for (int tt = 0; tt < 6; ++tt)                                          \
            DST[tt] = *(const half8_t*)(bp_ + roff[tt]);                        \
    }
#define MFMAB(SRC, B)                                                           \
    {                                                                           \
        const int kx_ = (B) >> 3, h_ = ((B) >> 2) & 1, cg_ = (B) & 3;           \
        _Pragma("unroll")                                                       \
        for (int ky = 0; ky < 3; ++ky) {                                        \
            const half8_t af_ = A[h_][ky * 3 + kx_];                            \
            _Pragma("unroll")                                                   \
            for (int rr = 0; rr < 4; ++rr)                                      \
                acc[rr][cg_] = __builtin_amdgcn_mfma_f32_16x16x32_f16(          \
                    SRC[rr + ky], af_, acc[rr][cg_], 0, 0, 0);                  \
        }                                                                       \
    }

    int s0 = P0 % NSLOT;
#pragma unroll 1
    for (int it = 0; it < 16; ++it) {
        // EARLY: issue next-tile main f32 loads, hold in regs across compute (T14)
        float4 ld[8];
        const int prn = P0 + it * 4 + 6 + rw;
        if (it < 15) stage_load(prn, ld);
        __builtin_amdgcn_sched_barrier(0);

        int roff[6];
#pragma unroll
        for (int tt = 0; tt < 6; ++tt) {
            int st = s0 + tt;
            if (st >= NSLOT) st -= NSLOT;
            roff[tt] = st * ROW_LDS;
        }

        floatx4 acc[4][4];
#pragma unroll
        for (int rr = 0; rr < 4; ++rr)
#pragma unroll
            for (int cgf = 0; cgf < 4; ++cgf) acc[rr][cgf] = (floatx4){bv, bv, bv, bv};

        // ---- software-pipelined 24 batches: load batch t+1 before MFMAs of t ----
        half8_t btA[6], btB[6];
        LOADB(btA, 0);
#pragma unroll
        for (int bb2 = 0; bb2 < 12; ++bb2) {
            const int b0 = bb2 * 2, b1 = bb2 * 2 + 1;
            LOADB(btB, b1);
            MFMAB(btA, b0);
            if (b1 + 1 < 24) LOADB(btA, b1 + 1);
            MFMAB(btB, b1);
        }

        // ---- epilogue: b128 scratch transpose -> full-line NT dwordx4 stores ----
        float* scr = &esc[wvid][0];
        float* obase = out + ((size_t)(n * 128 + wvid * 16)) * 65536 +
                       (size_t)(P0 + it * 4) * 256 + ow0;
#pragma unroll
        for (int rr = 0; rr < 4; ++rr) {
#pragma unroll
            for (int cgf = 0; cgf < 4; ++cgf)
                *(floatx4*)(scr + ln * 68 + cgf * 16 + g * 4) = acc[rr][cgf];
#pragma unroll
            for (int q = 0; q < 4; ++q) {
                const int co = q * 4 + g;
                const floatx4 v = *(const floatx4*)(scr + co * 68 + ln * 4);
                __builtin_nontemporal_store(
                    v, (floatx4*)(obase + (size_t)co * 65536 + rr * 256 + ln * 4));
            }
        }

        // ---- LATE: cvt + ds_write next tile (incl. inline edge); barrier publishes ----
        if (it < 15) {
            stage_write(prn, ld);
            asm volatile("s_waitcnt lgkmcnt(0)" ::: "memory");
            __builtin_amdgcn_s_barrier();
            __builtin_amdgcn_sched_barrier(0);
        }
        s0 += 4;
        if (s0 >= NSLOT) s0 -= NSLOT;
    }
#undef LOADB
#undef MFMAB
}

// ---------- fallback (proven V2 fp32) if workspace too small ----------
__global__ __launch_bounds__(256) void Conv2d_fallback_kernel(
    const float* __restrict__ x, const float* __restrict__ w,
    const float* __restrict__ bias, float* __restrict__ out) {
    const int tx = threadIdx.x & 15, ty = threadIdx.x >> 4;
    const int ow0 = blockIdx.x * 64 + tx * 4;
    const int oh = blockIdx.y * 16 + ty;
    const int gg = blockIdx.z & 7, n = blockIdx.z >> 3;
    const int co = gg * 16;
    float acc[16][4];
#pragma unroll
    for (int c = 0; c < 16; ++c) {
        const float b = bias[co + c];
#pragma unroll
        for (int p = 0; p < 4; ++p) acc[c][p] = b;
    }
    const float* xn = x + (size_t)n * CIN * HH * WW;
    const float* wb = w + (size_t)co * CIN * 9;
    for (int ci = 0; ci < CIN; ++ci) {
        const float* xc = xn + (size_t)ci * HH * WW;
        float in[3][6];
#pragma unroll
        for (int ky = 0; ky < 3; ++ky) {
            const int iy = oh + ky - 1;
            if ((unsigned)iy < (unsigned)HH) {
                const float* row = xc + iy * WW;
                const float4 v = *(const float4*)(row + ow0);
                in[ky][1] = v.x; in[ky][2] = v.y; in[ky][3] = v.z; in[ky][4] = v.w;
                in[ky][0] = (ow0 > 0) ? row[ow0 - 1] : 0.0f;
                in[ky][5] = (ow0 < WW - 4) ? row[ow0 + 4] : 0.0f;
            } else {
#pragma unroll
                for (int j = 0; j < 6; ++j) in[ky][j] = 0.0f;
            }
        }
        const float* wc2 = wb + ci * 9;
#pragma unroll
        for (int c = 0; c < 16; ++c) {
            const float* wcc = wc2 + (size_t)c * CIN * 9;
#pragma unroll
            for (int ky = 0; ky < 3; ++ky)
#pragma unroll
                for (int kx = 0; kx < 3; ++kx) {
                    const float wv2 = wcc[ky * 3 + kx];
#pragma unroll
                    for (int p = 0; p < 4; ++p) acc[c][p] += in[ky][kx + p] * wv2;
                }
        }
    }
    const size_t hw = (size_t)HH * WW;
    float* ob = out + ((size_t)n * COUT + co) * hw + (size_t)oh * WW + ow0;
#pragma unroll
    for (int c = 0; c < 16; ++c) {
        float4 v;
        v.x = acc[c][0]; v.y = acc[c][1]; v.z = acc[c][2]; v.w = acc[c][3];
        *(float4*)(ob + (size_t)c * hw) = v;
    }
}

extern "C" void kernel_launch(void* const* d_in, const int* in_sizes, int n_in,
                              void* d_out, int out_size, void* d_ws, size_t ws_size,
                              hipStream_t stream) {
    const float* x = (const float*)d_in[0];
    const float* w = (const float*)d_in[1];
    const float* b = (const float*)d_in[2];
    float* out = (float*)d_out;

    const size_t wt_bytes = (size_t)9 * 8 * 128 * 8 * 2;      // 144 KiB

    if (ws_size >= wt_bytes) {
        _Float16* w_t = (_Float16*)d_ws;
        Conv2d_wprep_kernel<<<dim3(288), 256, 0, stream>>>(w, w_t);
        Conv2dManual_77695958385099_kernel<<<dim3(4, 4, 16), 512, 0, stream>>>(
            x, w_t, b, out);
    } else {
        dim3 grid(WW / 64, HH / 16, NB * (COUT / 16));
        Conv2d_fallback_kernel<<<grid, 256, 0, stream>>>(x, w, b, out);
    }
}

// Round 13
// 748.569 us; speedup vs baseline: 1.1191x; 1.0326x over previous
//
#include <hip/hip_runtime.h>

// Conv2d 3x3 SAME, stride 1: x (16,64,256,256) f32, w (128,64,3,3), bias (128) -> out (16,128,256,256)
//
// V14 = V11 (best, 750us) + two surgical changes:
//  (a) Epilogue (esc transpose + NT stores) moved AFTER the per-iter barrier.
//      esc is per-wave private -> no cross-wave hazard. Removes the epilogue from the
//      barrier critical path, and the NT store burst now has a full compute phase to
//      drain before the next stage_write's (in-order) vmcnt wait can touch it.
//  (b) XCD co-location: the 4 col-strips of each (band,n) are placed at linear block ids
//      equal mod 8, so (assuming round-robin blockIdx->XCD) they share one XCD's L2.
//      V12 showed FETCH=416MB vs 285 ideal: the +46% is halo-column lines, which are
//      exactly the neighbor strip's main lines -> L2 hits once co-located.
//  Everything else V11-verbatim: fused f32->f16 staging (both-sides swizzle, edge e0/e1
//  loaded EARLY with the main loads), 10-slot ring, simple compiler-scheduled inner loop,
//  swapped mfma(bt,af,acc) D row=pixel, esc b128 transpose -> NT full-line stores,
//  raw s_barrier + lgkmcnt(0) only.

typedef _Float16 half8_t __attribute__((ext_vector_type(8)));
typedef float floatx4 __attribute__((ext_vector_type(4)));

#define HH 256
#define WW 256
#define CIN 64
#define COUT 128
#define NB 16

#define ROW_LDS 8448              // bytes per LDS tile row (66 cols * 128 B)
#define NSLOT   10

// ---------- pass 1a: weights OIHW f32 -> w_t[9][8][128][8] f16 ----------
__global__ void Conv2d_wprep_kernel(const float* __restrict__ w, _Float16* __restrict__ w_t) {
    int idx = blockIdx.x * 256 + threadIdx.x;
    if (idx >= 9 * 8 * 128 * 8) return;
    const int j = idx & 7, cout = (idx >> 3) & 127, s = (idx >> 10) & 7, t = idx >> 13;
    w_t[idx] = (_Float16)w[(cout * 64 + s * 8 + j) * 9 + t];
}

// ---------- fused conv ----------
__global__ __launch_bounds__(512, 2) void Conv2dManual_77695958385099_kernel(
    const float* __restrict__ x, const _Float16* __restrict__ w_t,
    const float* __restrict__ bias, float* __restrict__ out) {
    __shared__ __align__(16) unsigned char xs[NSLOT * ROW_LDS];  // 84480 B
    __shared__ __align__(16) float esc[8][1088];                 // 34816 B
    const int tid = threadIdx.x;
    const int l = tid & 63, wvid = tid >> 6;    // wave -> couts wvid*16..+15
    const int g = l >> 4, ln = l & 15;

    // ---- XCD co-location decode: strips of one (band,n) share blockid mod 8 ----
    const int blin = blockIdx.x;                // 0..255
    const int g8 = blin & 7;                    // low 3 bits -> XCD (round-robin assumption)
    const int r = blin >> 3;
    const int strip = r & 3;                    // 4 strips of a group -> same g8 -> same XCD
    const int ghi = r >> 2;                     // 0..7
    const int group = g8 + 8 * ghi;             // 0..63
    const int band = group & 3;
    const int n = group >> 2;

    const int ow0 = strip * 64;
    const int P0 = band * 64;

    // staging roles: 4 row-groups of 128 threads
    const int rw = tid >> 7;
    const int t7 = tid & 127;
    const int su = t7 & 7;                      // ci-unit (8 ci)
    const int cb = t7 >> 3;                     // col block 0..15 (4 cols each)
    const bool isEdge = (t7 >= 120);            // 8 lanes/row-group handle halo cols
    const int eu = t7 - 120;

    // ---- persistent weights: A[h][tap], 18 x half8 = 72 VGPR ----
    const char* wl = (const char*)w_t + g * 2048 + (wvid * 16 + ln) * 16;
    half8_t A[2][9];
#pragma unroll
    for (int h = 0; h < 2; ++h)
#pragma unroll
        for (int tp = 0; tp < 9; ++tp)
            A[h][tp] = *(const half8_t*)(wl + h * 8192 + tp * 16384);

    const float bv = bias[wvid * 16 + ln];

    // ---- per-lane LDS byte offsets: F[cgf][kx][h] (verified formula) ----
    int F[4][3][2];
#pragma unroll
    for (int cgf = 0; cgf < 4; ++cgf)
#pragma unroll
        for (int kx = 0; kx < 3; ++kx)
#pragma unroll
            for (int h = 0; h < 2; ++h) {
                const int c = cgf * 16 + kx + ln;
                F[cgf][kx][h] = c * 128 + (((4 * h + g) ^ (c & 7)) << 4);
            }

    // ---- staging helpers (V11-verbatim: edge loaded EARLY with main) ----
    auto stage_load = [&](int pr, float4 (&ld)[8], float (&e0)[8], float (&e1)[8]) {
        const int gr = pr - 1;
        const bool vrow = ((unsigned)gr < 256u);
        if (vrow) {
            const float4* xr = (const float4*)x +
                               (((size_t)(n * 64 + su * 8)) << 14) +
                               (size_t)gr * 64 + (ow0 >> 2) + cb;
#pragma unroll
            for (int j = 0; j < 8; ++j) ld[j] = xr[(size_t)j << 14];
        } else {
#pragma unroll
            for (int j = 0; j < 8; ++j) ld[j] = (float4){0.f, 0.f, 0.f, 0.f};
        }
        if (isEdge) {
            const float* xe = x + (((size_t)(n * 64 + eu * 8)) << 16) + (size_t)gr * 256;
#pragma unroll
            for (int j = 0; j < 8; ++j) {
                e0[j] = (vrow && ow0 > 0)        ? xe[((size_t)j << 16) + ow0 - 1]  : 0.f;
                e1[j] = (vrow && ow0 + 64 < 256) ? xe[((size_t)j << 16) + ow0 + 64] : 0.f;
            }
        }
    };
    auto stage_write = [&](int pr, const float4 (&ld)[8], const float (&e0)[8],
                           const float (&e1)[8]) {
        const unsigned sb = (unsigned)(pr % NSLOT) * ROW_LDS;
#pragma unroll
        for (int k = 0; k < 4; ++k) {
            const int c = 1 + cb * 4 + k;
            half8_t hv;
#pragma unroll
            for (int j = 0; j < 8; ++j) hv[j] = (_Float16)((const float*)&ld[j])[k];
            *(half8_t*)(xs + sb + c * 128 + ((su ^ (c & 7)) << 4)) = hv;
        }
        if (isEdge) {
            half8_t h0, h1;
#pragma unroll
            for (int j = 0; j < 8; ++j) {
                h0[j] = (_Float16)e0[j];
                h1[j] = (_Float16)e1[j];
            }
            *(half8_t*)(xs + sb + (eu << 4)) = h0;                      // c = 0
            *(half8_t*)(xs + sb + 65 * 128 + ((eu ^ 1) << 4)) = h1;     // c = 65
        }
    };

    // ---- prologue: stage padded rows P0..P0+5 ----
    {
        float4 ld[8]; float e0[8], e1[8];
        stage_load(P0 + rw, ld, e0, e1);
        stage_write(P0 + rw, ld, e0, e1);
        if (rw < 2) {
            stage_load(P0 + 4 + rw, ld, e0, e1);
            stage_write(P0 + 4 + rw, ld, e0, e1);
        }
    }
    asm volatile("s_waitcnt lgkmcnt(0)" ::: "memory");
    __builtin_amdgcn_s_barrier();
    __builtin_amdgcn_sched_barrier(0);

    int s0 = P0 % NSLOT;
#pragma unroll 1
    for (int it = 0; it < 16; ++it) {
        // ---- EARLY: issue next-tile f32 loads, hold in regs across compute (T14) ----
        float4 ld[8]; float e0[8], e1[8];
        const int prn = P0 + it * 4 + 6 + rw;
        if (it < 15) stage_load(prn, ld, e0, e1);
        __builtin_amdgcn_sched_barrier(0);

        int roff[6];
#pragma unroll
        for (int tt = 0; tt < 6; ++tt) {
            int st = s0 + tt;
            if (st >= NSLOT) st -= NSLOT;
            roff[tt] = st * ROW_LDS;
        }

        floatx4 acc[4][4];
#pragma unroll
        for (int rr = 0; rr < 4; ++rr)
#pragma unroll
            for (int cgf = 0; cgf < 4; ++cgf) acc[rr][cgf] = (floatx4){bv, bv, bv, bv};

        // ---- compute (simple, compiler-scheduled — V11-verbatim) ----
#pragma unroll
        for (int kx = 0; kx < 3; ++kx)
#pragma unroll
            for (int h = 0; h < 2; ++h)
#pragma unroll
                for (int cgf = 0; cgf < 4; ++cgf) {
                    const unsigned char* bp = xs + F[cgf][kx][h];
                    half8_t bt[6];
#pragma unroll
                    for (int tt = 0; tt < 6; ++tt)
                        bt[tt] = *(const half8_t*)(bp + roff[tt]);
#pragma unroll
                    for (int ky = 0; ky < 3; ++ky) {
                        const half8_t af = A[h][ky * 3 + kx];
#pragma unroll
                        for (int rr = 0; rr < 4; ++rr)
                            acc[rr][cgf] = __builtin_amdgcn_mfma_f32_16x16x32_f16(
                                bt[rr + ky], af, acc[rr][cgf], 0, 0, 0);  // D row=pixel
                    }
                }

        // ---- stage_write + barrier FIRST (epilogue off the barrier path) ----
        if (it < 15) {
            stage_write(prn, ld, e0, e1);   // vmcnt wait here sees loads only in flight
            asm volatile("s_waitcnt lgkmcnt(0)" ::: "memory");
            __builtin_amdgcn_s_barrier();
            __builtin_amdgcn_sched_barrier(0);
        }

        // ---- epilogue AFTER barrier: esc (per-wave private) + NT full-line stores;
        //      stores drain during the next iter's compute ----
        float* scr = &esc[wvid][0];
        float* obase = out + ((size_t)(n * 128 + wvid * 16)) * 65536 +
                       (size_t)(P0 + it * 4) * 256 + ow0;
#pragma unroll
        for (int rr = 0; rr < 4; ++rr) {
#pragma unroll
            for (int cgf = 0; cgf < 4; ++cgf)
                *(floatx4*)(scr + ln * 68 + cgf * 16 + g * 4) = acc[rr][cgf];
#pragma unroll
            for (int q = 0; q < 4; ++q) {
                const int co = q * 4 + g;
                const floatx4 v = *(const floatx4*)(scr + co * 68 + ln * 4);
                __builtin_nontemporal_store(
                    v, (floatx4*)(obase + (size_t)co * 65536 + rr * 256 + ln * 4));
            }
        }

        s0 += 4;
        if (s0 >= NSLOT) s0 -= NSLOT;
    }
}

// ---------- fallback (proven V2 fp32) if workspace too small ----------
__global__ __launch_bounds__(256) void Conv2d_fallback_kernel(
    const float* __restrict__ x, const float* __restrict__ w,
    const float* __restrict__ bias, float* __restrict__ out) {
    const int tx = threadIdx.x & 15, ty = threadIdx.x >> 4;
    const int ow0 = blockIdx.x * 64 + tx * 4;
    const int oh = blockIdx.y * 16 + ty;
    const int gg = blockIdx.z & 7, n = blockIdx.z >> 3;
    const int co = gg * 16;
    float acc[16][4];
#pragma unroll
    for (int c = 0; c < 16; ++c) {
        const float b = bias[co + c];
#pragma unroll
        for (int p = 0; p < 4; ++p) acc[c][p] = b;
    }
    const float* xn = x + (size_t)n * CIN * HH * WW;
    const float* wb = w + (size_t)co * CIN * 9;
    for (int ci = 0; ci < CIN; ++ci) {
        const float* xc = xn + (size_t)ci * HH * WW;
        float in[3][6];
#pragma unroll
        for (int ky = 0; ky < 3; ++ky) {
            const int iy = oh + ky - 1;
            if ((unsigned)iy < (unsigned)HH) {
                const float* row = xc + iy * WW;
                const float4 v = *(const float4*)(row + ow0);
                in[ky][1] = v.x; in[ky][2] = v.y; in[ky][3] = v.z; in[ky][4] = v.w;
                in[ky][0] = (ow0 > 0) ? row[ow0 - 1] : 0.0f;
                in[ky][5] = (ow0 < WW - 4) ? row[ow0 + 4] : 0.0f;
            } else {
#pragma unroll
                for (int j = 0; j < 6; ++j) in[ky][j] = 0.0f;
            }
        }
        const float* wc2 = wb + ci * 9;
#pragma unroll
        for (int c = 0; c < 16; ++c) {
            const float* wcc = wc2 + (size_t)c * CIN * 9;
#pragma unroll
            for (int ky = 0; ky < 3; ++ky)
#pragma unroll
                for (int kx = 0; kx < 3; ++kx) {
                    const float wv2 = wcc[ky * 3 + kx];
#pragma unroll
                    for (int p = 0; p < 4; ++p) acc[c][p] += in[ky][kx + p] * wv2;
                }
        }
    }
    const size_t hw = (size_t)HH * WW;
    float* ob = out + ((size_t)n * COUT + co) * hw + (size_t)oh * WW + ow0;
#pragma unroll
    for (int c = 0; c < 16; ++c) {
        float4 v;
        v.x = acc[c][0]; v.y = acc[c][1]; v.z = acc[c][2]; v.w = acc[c][3];
        *(float4*)(ob + (size_t)c * hw) = v;
    }
}

extern "C" void kernel_launch(void* const* d_in, const int* in_sizes, int n_in,
                              void* d_out, int out_size, void* d_ws, size_t ws_size,
                              hipStream_t stream) {
    const float* x = (const float*)d_in[0];
    const float* w = (const float*)d_in[1];
    const float* b = (const float*)d_in[2];
    float* out = (float*)d_out;

    const size_t wt_bytes = (size_t)9 * 8 * 128 * 8 * 2;      // 144 KiB

    if (ws_size >= wt_bytes) {
        _Float16* w_t = (_Float16*)d_ws;
        Conv2d_wprep_kernel<<<dim3(288), 256, 0, stream>>>(w, w_t);
        Conv2dManual_77695958385099_kernel<<<dim3(256), 512, 0, stream>>>(
            x, w_t, b, out);
    } else {
        dim3 grid(WW / 64, HH / 16, NB * (COUT / 16));
        Conv2d_fallback_kernel<<<grid, 256, 0, stream>>>(x, w, b, out);
    }
}

// Round 14
// 731.291 us; speedup vs baseline: 1.1456x; 1.0236x over previous
//
#include <hip/hip_runtime.h>

// Conv2d 3x3 SAME, stride 1: x (16,64,256,256) f32, w (128,64,3,3), bias (128) -> out (16,128,256,256)
//
// V15 = V14 with CACHED (non-NT) output stores.
//  Mechanism: vmcnt is in-order. Per iter, epilogue stores(t-1) precede stage_load(t+1);
//  stage_write(t+1)'s wait for the loads therefore requires the older stores retired.
//  NT stores retire only at HBM-ack (~5.3us/CU/iter of drain, > the 4.7us compute phase)
//  -> synchronous drain stall every iteration. Cached stores ack at L2 (~200cyc); the
//  L2->HBM writeback is asynchronous and off the critical path. NT's original purpose
//  (protect x_p L3 residency) is obsolete: V11+ has no x_p; x is streamed read-once.
//  Everything else V14-verbatim: fused f32->f16 staging (both-sides swizzle), 10-slot
//  ring, XCD strip co-location, swapped mfma(bt,af,acc) D row=pixel, esc b128 transpose,
//  full-128B-line dwordx4 stores, epilogue after barrier, raw s_barrier + lgkmcnt(0).

typedef _Float16 half8_t __attribute__((ext_vector_type(8)));
typedef float floatx4 __attribute__((ext_vector_type(4)));

#define HH 256
#define WW 256
#define CIN 64
#define COUT 128
#define NB 16

#define ROW_LDS 8448              // bytes per LDS tile row (66 cols * 128 B)
#define NSLOT   10

// ---------- pass 1a: weights OIHW f32 -> w_t[9][8][128][8] f16 ----------
__global__ void Conv2d_wprep_kernel(const float* __restrict__ w, _Float16* __restrict__ w_t) {
    int idx = blockIdx.x * 256 + threadIdx.x;
    if (idx >= 9 * 8 * 128 * 8) return;
    const int j = idx & 7, cout = (idx >> 3) & 127, s = (idx >> 10) & 7, t = idx >> 13;
    w_t[idx] = (_Float16)w[(cout * 64 + s * 8 + j) * 9 + t];
}

// ---------- fused conv ----------
__global__ __launch_bounds__(512, 2) void Conv2dManual_77695958385099_kernel(
    const float* __restrict__ x, const _Float16* __restrict__ w_t,
    const float* __restrict__ bias, float* __restrict__ out) {
    __shared__ __align__(16) unsigned char xs[NSLOT * ROW_LDS];  // 84480 B
    __shared__ __align__(16) float esc[8][1088];                 // 34816 B
    const int tid = threadIdx.x;
    const int l = tid & 63, wvid = tid >> 6;    // wave -> couts wvid*16..+15
    const int g = l >> 4, ln = l & 15;

    // ---- XCD co-location decode: strips of one (band,n) share blockid mod 8 ----
    const int blin = blockIdx.x;                // 0..255
    const int g8 = blin & 7;
    const int r = blin >> 3;
    const int strip = r & 3;
    const int ghi = r >> 2;
    const int group = g8 + 8 * ghi;             // 0..63
    const int band = group & 3;
    const int n = group >> 2;

    const int ow0 = strip * 64;
    const int P0 = band * 64;

    // staging roles: 4 row-groups of 128 threads
    const int rw = tid >> 7;
    const int t7 = tid & 127;
    const int su = t7 & 7;                      // ci-unit (8 ci)
    const int cb = t7 >> 3;                     // col block 0..15 (4 cols each)
    const bool isEdge = (t7 >= 120);            // 8 lanes/row-group handle halo cols
    const int eu = t7 - 120;

    // ---- persistent weights: A[h][tap], 18 x half8 = 72 VGPR ----
    const char* wl = (const char*)w_t + g * 2048 + (wvid * 16 + ln) * 16;
    half8_t A[2][9];
#pragma unroll
    for (int h = 0; h < 2; ++h)
#pragma unroll
        for (int tp = 0; tp < 9; ++tp)
            A[h][tp] = *(const half8_t*)(wl + h * 8192 + tp * 16384);

    const float bv = bias[wvid * 16 + ln];

    // ---- per-lane LDS byte offsets: F[cgf][kx][h] (verified formula) ----
    int F[4][3][2];
#pragma unroll
    for (int cgf = 0; cgf < 4; ++cgf)
#pragma unroll
        for (int kx = 0; kx < 3; ++kx)
#pragma unroll
            for (int h = 0; h < 2; ++h) {
                const int c = cgf * 16 + kx + ln;
                F[cgf][kx][h] = c * 128 + (((4 * h + g) ^ (c & 7)) << 4);
            }

    // ---- staging helpers (edge loaded EARLY with main) ----
    auto stage_load = [&](int pr, float4 (&ld)[8], float (&e0)[8], float (&e1)[8]) {
        const int gr = pr - 1;
        const bool vrow = ((unsigned)gr < 256u);
        if (vrow) {
            const float4* xr = (const float4*)x +
                               (((size_t)(n * 64 + su * 8)) << 14) +
                               (size_t)gr * 64 + (ow0 >> 2) + cb;
#pragma unroll
            for (int j = 0; j < 8; ++j) ld[j] = xr[(size_t)j << 14];
        } else {
#pragma unroll
            for (int j = 0; j < 8; ++j) ld[j] = (float4){0.f, 0.f, 0.f, 0.f};
        }
        if (isEdge) {
            const float* xe = x + (((size_t)(n * 64 + eu * 8)) << 16) + (size_t)gr * 256;
#pragma unroll
            for (int j = 0; j < 8; ++j) {
                e0[j] = (vrow && ow0 > 0)        ? xe[((size_t)j << 16) + ow0 - 1]  : 0.f;
                e1[j] = (vrow && ow0 + 64 < 256) ? xe[((size_t)j << 16) + ow0 + 64] : 0.f;
            }
        }
    };
    auto stage_write = [&](int pr, const float4 (&ld)[8], const float (&e0)[8],
                           const float (&e1)[8]) {
        const unsigned sb = (unsigned)(pr % NSLOT) * ROW_LDS;
#pragma unroll
        for (int k = 0; k < 4; ++k) {
            const int c = 1 + cb * 4 + k;
            half8_t hv;
#pragma unroll
            for (int j = 0; j < 8; ++j) hv[j] = (_Float16)((const float*)&ld[j])[k];
            *(half8_t*)(xs + sb + c * 128 + ((su ^ (c & 7)) << 4)) = hv;
        }
        if (isEdge) {
            half8_t h0, h1;
#pragma unroll
            for (int j = 0; j < 8; ++j) {
                h0[j] = (_Float16)e0[j];
                h1[j] = (_Float16)e1[j];
            }
            *(half8_t*)(xs + sb + (eu << 4)) = h0;                      // c = 0
            *(half8_t*)(xs + sb + 65 * 128 + ((eu ^ 1) << 4)) = h1;     // c = 65
        }
    };

    // ---- prologue: stage padded rows P0..P0+5 ----
    {
        float4 ld[8]; float e0[8], e1[8];
        stage_load(P0 + rw, ld, e0, e1);
        stage_write(P0 + rw, ld, e0, e1);
        if (rw < 2) {
            stage_load(P0 + 4 + rw, ld, e0, e1);
            stage_write(P0 + 4 + rw, ld, e0, e1);
        }
    }
    asm volatile("s_waitcnt lgkmcnt(0)" ::: "memory");
    __builtin_amdgcn_s_barrier();
    __builtin_amdgcn_sched_barrier(0);

    int s0 = P0 % NSLOT;
#pragma unroll 1
    for (int it = 0; it < 16; ++it) {
        // ---- EARLY: issue next-tile f32 loads, hold in regs across compute (T14) ----
        float4 ld[8]; float e0[8], e1[8];
        const int prn = P0 + it * 4 + 6 + rw;
        if (it < 15) stage_load(prn, ld, e0, e1);
        __builtin_amdgcn_sched_barrier(0);

        int roff[6];
#pragma unroll
        for (int tt = 0; tt < 6; ++tt) {
            int st = s0 + tt;
            if (st >= NSLOT) st -= NSLOT;
            roff[tt] = st * ROW_LDS;
        }

        floatx4 acc[4][4];
#pragma unroll
        for (int rr = 0; rr < 4; ++rr)
#pragma unroll
            for (int cgf = 0; cgf < 4; ++cgf) acc[rr][cgf] = (floatx4){bv, bv, bv, bv};

        // ---- compute (simple, compiler-scheduled) ----
#pragma unroll
        for (int kx = 0; kx < 3; ++kx)
#pragma unroll
            for (int h = 0; h < 2; ++h)
#pragma unroll
                for (int cgf = 0; cgf < 4; ++cgf) {
                    const unsigned char* bp = xs + F[cgf][kx][h];
                    half8_t bt[6];
#pragma unroll
                    for (int tt = 0; tt < 6; ++tt)
                        bt[tt] = *(const half8_t*)(bp + roff[tt]);
#pragma unroll
                    for (int ky = 0; ky < 3; ++ky) {
                        const half8_t af = A[h][ky * 3 + kx];
#pragma unroll
                        for (int rr = 0; rr < 4; ++rr)
                            acc[rr][cgf] = __builtin_amdgcn_mfma_f32_16x16x32_f16(
                                bt[rr + ky], af, acc[rr][cgf], 0, 0, 0);  // D row=pixel
                    }
                }

        // ---- stage_write + barrier FIRST (epilogue off the barrier path) ----
        if (it < 15) {
            stage_write(prn, ld, e0, e1);
            asm volatile("s_waitcnt lgkmcnt(0)" ::: "memory");
            __builtin_amdgcn_s_barrier();
            __builtin_amdgcn_sched_barrier(0);
        }

        // ---- epilogue AFTER barrier: esc transpose -> CACHED full-line stores.
        //      Stores ack at L2; L2->HBM writeback drains asynchronously. ----
        float* scr = &esc[wvid][0];
        float* obase = out + ((size_t)(n * 128 + wvid * 16)) * 65536 +
                       (size_t)(P0 + it * 4) * 256 + ow0;
#pragma unroll
        for (int rr = 0; rr < 4; ++rr) {
#pragma unroll
            for (int cgf = 0; cgf < 4; ++cgf)
                *(floatx4*)(scr + ln * 68 + cgf * 16 + g * 4) = acc[rr][cgf];
#pragma unroll
            for (int q = 0; q < 4; ++q) {
                const int co = q * 4 + g;
                const floatx4 v = *(const floatx4*)(scr + co * 68 + ln * 4);
                *(floatx4*)(obase + (size_t)co * 65536 + rr * 256 + ln * 4) = v;
            }
        }

        s0 += 4;
        if (s0 >= NSLOT) s0 -= NSLOT;
    }
}

// ---------- fallback (proven V2 fp32) if workspace too small ----------
__global__ __launch_bounds__(256) void Conv2d_fallback_kernel(
    const float* __restrict__ x, const float* __restrict__ w,
    const float* __restrict__ bias, float* __restrict__ out) {
    const int tx = threadIdx.x & 15, ty = threadIdx.x >> 4;
    const int ow0 = blockIdx.x * 64 + tx * 4;
    const int oh = blockIdx.y * 16 + ty;
    const int gg = blockIdx.z & 7, n = blockIdx.z >> 3;
    const int co = gg * 16;
    float acc[16][4];
#pragma unroll
    for (int c = 0; c < 16; ++c) {
        const float b = bias[co + c];
#pragma unroll
        for (int p = 0; p < 4; ++p) acc[c][p] = b;
    }
    const float* xn = x + (size_t)n * CIN * HH * WW;
    const float* wb = w + (size_t)co * CIN * 9;
    for (int ci = 0; ci < CIN; ++ci) {
        const float* xc = xn + (size_t)ci * HH * WW;
        float in[3][6];
#pragma unroll
        for (int ky = 0; ky < 3; ++ky) {
            const int iy = oh + ky - 1;
            if ((unsigned)iy < (unsigned)HH) {
                const float* row = xc + iy * WW;
                const float4 v = *(const float4*)(row + ow0);
                in[ky][1] = v.x; in[ky][2] = v.y; in[ky][3] = v.z; in[ky][4] = v.w;
                in[ky][0] = (ow0 > 0) ? row[ow0 - 1] : 0.0f;
                in[ky][5] = (ow0 < WW - 4) ? row[ow0 + 4] : 0.0f;
            } else {
#pragma unroll
                for (int j = 0; j < 6; ++j) in[ky][j] = 0.0f;
            }
        }
        const float* wc2 = wb + ci * 9;
#pragma unroll
        for (int c = 0; c < 16; ++c) {
            const float* wcc = wc2 + (size_t)c * CIN * 9;
#pragma unroll
            for (int ky = 0; ky < 3; ++ky)
#pragma unroll
                for (int kx = 0; kx < 3; ++kx) {
                    const float wv2 = wcc[ky * 3 + kx];
#pragma unroll
                    for (int p = 0; p < 4; ++p) acc[c][p] += in[ky][kx + p] * wv2;
                }
        }
    }
    const size_t hw = (size_t)HH * WW;
    float* ob = out + ((size_t)n * COUT + co) * hw + (size_t)oh * WW + ow0;
#pragma unroll
    for (int c = 0; c < 16; ++c) {
        float4 v;
        v.x = acc[c][0]; v.y = acc[c][1]; v.z = acc[c][2]; v.w = acc[c][3];
        *(float4*)(ob + (size_t)c * hw) = v;
    }
}

extern "C" void kernel_launch(void* const* d_in, const int* in_sizes, int n_in,
                              void* d_out, int out_size, void* d_ws, size_t ws_size,
                              hipStream_t stream) {
    const float* x = (const float*)d_in[0];
    const float* w = (const float*)d_in[1];
    const float* b = (const float*)d_in[2];
    float* out = (float*)d_out;

    const size_t wt_bytes = (size_t)9 * 8 * 128 * 8 * 2;      // 144 KiB

    if (ws_size >= wt_bytes) {
        _Float16* w_t = (_Float16*)d_ws;
        Conv2d_wprep_kernel<<<dim3(288), 256, 0, stream>>>(w, w_t);
        Conv2dManual_77695958385099_kernel<<<dim3(256), 512, 0, stream>>>(
            x, w_t, b, out);
    } else {
        dim3 grid(WW / 64, HH / 16, NB * (COUT / 16));
        Conv2d_fallback_kernel<<<grid, 256, 0, stream>>>(x, w, b, out);
    }
}